// Round 17
// baseline (226.891 us; speedup 1.0000x reference)
//
#include <hip/hip_runtime.h>
#include <hip/hip_bf16.h>
#include <stdint.h>

#define NB 32
#define NS 2048
#define ND 1024
#define NA 1024
#define MASK_NEG 1e30f

#define BM 256
#define BN 256
#define BK 64
#define NTILES 64  // 4 a-tiles x 16 K-tiles

typedef __attribute__((ext_vector_type(4))) float f32x4;
typedef __attribute__((ext_vector_type(8))) __bf16 bf16x8;

__device__ __forceinline__ void glds16(const void* g, void* l) {
  __builtin_amdgcn_global_load_lds(
      (const __attribute__((address_space(1))) uint32_t*)g,
      (__attribute__((address_space(3))) uint32_t*)(uintptr_t)l, 16, 0, 0);
}

// ---------------- zero scores (atomic accumulation target) ----------------
__global__ void zero_f32(float* __restrict__ p, int n) {
  int i = blockIdx.x * 256 + threadIdx.x;
  if (i < n) p[i] = 0.f;
}

// ---------------- fp32 -> bf16 bulk convert (W2 only, 2 MB) ----------------
__global__ __launch_bounds__(256) void cvt_bf16(const float* __restrict__ in,
                                                __bf16* __restrict__ out, int n8) {
  long i = blockIdx.x * 256 + threadIdx.x;
  const long stride = (long)gridDim.x * 256;
  for (; i < n8; i += stride) {
    f32x4 a = ((const f32x4*)in)[2 * i];
    f32x4 b = ((const f32x4*)in)[2 * i + 1];
    bf16x8 o;
#pragma unroll
    for (int j = 0; j < 4; ++j) { o[j] = (__bf16)a[j]; o[4 + j] = (__bf16)b[j]; }
    ((bf16x8*)out)[i] = o;
  }
}

// ---------------- w1q[b,a] = query[b,:] . W1[a,:]  (fp32) ----------------
__global__ __launch_bounds__(256) void w1q_kernel(const float* __restrict__ q,
                                                  const float* __restrict__ W1,
                                                  float* __restrict__ w1q) {
  const int b = blockIdx.x;
  const int a0 = blockIdx.y * 64;
  const int t = threadIdx.x;
  const int al = t >> 2;
  const int part = t & 3;
  const float* wrow = W1 + (size_t)(a0 + al) * ND + part * 256;
  const float* qrow = q + (size_t)b * ND + part * 256;
  float sum = 0.f;
#pragma unroll 8
  for (int i = 0; i < 256; i += 4) {
    float4 w = *reinterpret_cast<const float4*>(wrow + i);
    float4 x = *reinterpret_cast<const float4*>(qrow + i);
    sum += w.x * x.x + w.y * x.y + w.z * x.z + w.w * x.w;
  }
  __shared__ float red[256];
  red[t] = sum;
  __syncthreads();
  if (t < 64) {
    w1q[(size_t)b * NA + a0 + t] = red[t * 4] + red[t * 4 + 1] + red[t * 4 + 2] + red[t * 4 + 3];
  }
}

// ---------------- fused scores GEMM: fp32-direct A, 4Mx2N, 2-phase ----------------
// R16 base (fp32 keys staged straight to LDS, no cvt kernel; A fp32 quarters
// ring-6 slot (4T+q)%6; B bf16 halves ring-4 slot (2T+h)%4; 160 KB LDS;
// 4Mx2N waves: wave = 64 rows x 128 cols) with ONE change: 4 phases -> 2
// phases of 32 MFMA. Per tile: 4 BAR + 2 lgkm-pins + 1 vmcnt (was 8+4+1) --
// halves the CU-wide sync rendezvous cost, the dominant non-MFMA term.
// WAR legality: all af reads issue in ph1 and are completion-proven by ph1's
// lgkm(0); ph1's END-BAR is after every wave's lgkm -> ph2's restage of tau's
// q0/q1 slots is race-free (same discipline as R16, once per tile).
// Staging: ph1 {A q0,q1(tau+1); B h0(tau+1)}, ph2 {A q2,q3(tau+1); B h1(tau+1)};
// vmcnt(0) at ph2-end (ph2 stages get a full ~2000 cyc phase of flight).
// Swizzles (R12/R16-verified): A store col16=(t&15)^((t>>4)&15), read unit
// (ko*2(+1))^lrow / (8+ko*2(+1))^lrow; B store (t&7)^((t>>3)&7), read
// (kk*4+ko)^(lrow&7).
__global__ __launch_bounds__(512, 1) void score_gemm(
    const float* __restrict__ keysf, const __bf16* __restrict__ W2b,
    const float* __restrict__ w1q, const float* __restrict__ vvec,
    float* __restrict__ scores) {
  __shared__ __attribute__((aligned(1024))) char ldsA[6 * 16384];  // 96 KB fp32 quarters
  __shared__ __attribute__((aligned(1024))) char ldsB[4 * 16384];  // 64 KB bf16 halves

  const int t = threadIdx.x;
  const int bs0 = blockIdx.x * BM;
  const int b = bs0 >> 11;  // / NS
  const int lane = t & 63;
  const int wid = t >> 6;
  const int wr = wid >> 1;   // 0..3: 64-row quarter of output (= A quarter)
  const int wc = wid & 1;    // 0..1: 128-col half of output (= B half)
  const int lrow = lane & 15;
  const int ko = lane >> 4;

  // staging maps (thread-linear LDS dest, inverse-swizzled global source)
  const int rowA = t >> 4;                   // 0..31 (A: 16 units/256B row)
  const int scolA = (t & 15) ^ (rowA & 15);  // col16 unit (4 floats)
  const int rowB = t >> 3;                   // 0..63 (B: 8 units/128B row)
  const int scolB = (t & 7) ^ (rowB & 7);    // col16 unit (8 bf16)

  // fragment read units (pre-swizzled; frag rows fi*16+lrow -> row&15 == lrow)
  const int sA00 = (ko * 2) ^ lrow, sA01 = (ko * 2 + 1) ^ lrow;
  const int sA10 = (8 + ko * 2) ^ lrow, sA11 = (8 + ko * 2 + 1) ^ lrow;
  const int sB0 = ko ^ (lrow & 7), sB1 = (4 + ko) ^ (lrow & 7);

  f32x4 acc[4][8];
#pragma unroll
  for (int mi = 0; mi < 4; ++mi)
#pragma unroll
    for (int ni = 0; ni < 8; ++ni) acc[mi][ni] = f32x4{0.f, 0.f, 0.f, 0.f};

  bf16x8 af[4][2], bfr[4][2];

#define STAGE_A(T, Q)                                                           \
  do {                                                                          \
    if ((T) < NTILES) {                                                         \
      const unsigned slot_ = (4u * (unsigned)(T) + (unsigned)(Q)) % 6u;         \
      char* d_ = ldsA + slot_ * 16384 + t * 16;                                 \
      const size_t r0_ = (size_t)(bs0 + (Q)*64 + rowA);                         \
      const int kf_ = ((T)&15) * 64 + scolA * 4;                                \
      glds16(keysf + r0_ * ND + kf_, d_);                                       \
      glds16(keysf + (r0_ + 32) * ND + kf_, d_ + 8192);                         \
    }                                                                           \
  } while (0)

#define STAGE_B(T, H)                                                           \
  do {                                                                          \
    if ((T) < NTILES) {                                                         \
      const unsigned slot_ = (2u * (unsigned)(T) + (unsigned)(H)) % 4u;         \
      char* d_ = ldsB + slot_ * 16384 + t * 16;                                 \
      const size_t r0_ = (size_t)(((T) >> 4) * 256 + (H)*128 + rowB);           \
      const int ke_ = (((T)&15) * 64) + scolB * 8;                              \
      glds16(W2b + r0_ * ND + ke_, d_);                                         \
      glds16(W2b + (r0_ + 64) * ND + ke_, d_ + 8192);                           \
    }                                                                           \
  } while (0)

#define SB_ __builtin_amdgcn_sched_barrier(0)
#define P1 __builtin_amdgcn_s_setprio(1)
#define P0 __builtin_amdgcn_s_setprio(0)
#define BAR __builtin_amdgcn_s_barrier()

  // PHASE HP_ (0/1): stage -> [HP0: all 16 A-frag reads + cvt] -> 8 B-frags
  // (ni HP*4..HP*4+3) -> BAR -> lgkm(0) -> 32 MFMA -> [HP1: vmcnt(0)] -> BAR.
#define PHASE(HP_, STAGES)                                                      \
  do {                                                                          \
    STAGES;                                                                     \
    if ((HP_) == 0) {                                                           \
      const char* Ab_ = ldsA + ((4u * (unsigned)tau + (unsigned)wr) % 6u) * 16384; \
      _Pragma("unroll") for (int mi = 0; mi < 4; ++mi) {                        \
        const int rb_ = (mi * 16 + lrow) * 256;                                 \
        f32x4 l0 = *reinterpret_cast<const f32x4*>(Ab_ + rb_ + sA00 * 16);      \
        f32x4 l1 = *reinterpret_cast<const f32x4*>(Ab_ + rb_ + sA01 * 16);      \
        f32x4 h0 = *reinterpret_cast<const f32x4*>(Ab_ + rb_ + sA10 * 16);      \
        f32x4 h1 = *reinterpret_cast<const f32x4*>(Ab_ + rb_ + sA11 * 16);      \
        _Pragma("unroll") for (int j = 0; j < 4; ++j) {                         \
          af[mi][0][j] = (__bf16)l0[j]; af[mi][0][4 + j] = (__bf16)l1[j];       \
          af[mi][1][j] = (__bf16)h0[j]; af[mi][1][4 + j] = (__bf16)h1[j];       \
        }                                                                       \
      }                                                                         \
    }                                                                           \
    {                                                                           \
      const char* Bb_ = ldsB + ((2u * (unsigned)tau + (unsigned)wc) % 4u) * 16384; \
      _Pragma("unroll") for (int nq = 0; nq < 4; ++nq) {                        \
        const int rb_ = (((HP_)*4 + nq) * 16 + lrow) * 128;                     \
        bfr[nq][0] = *reinterpret_cast<const bf16x8*>(Bb_ + rb_ + sB0 * 16);    \
        bfr[nq][1] = *reinterpret_cast<const bf16x8*>(Bb_ + rb_ + sB1 * 16);    \
      }                                                                         \
    }                                                                           \
    BAR;                                                                        \
    asm volatile("s_waitcnt lgkmcnt(0)");                                       \
    SB_;                                                                        \
    P1;                                                                         \
    _Pragma("unroll") for (int mi = 0; mi < 4; ++mi)                            \
        _Pragma("unroll") for (int nq = 0; nq < 4; ++nq) {                      \
      acc[mi][(HP_)*4 + nq] = __builtin_amdgcn_mfma_f32_16x16x32_bf16(          \
          af[mi][0], bfr[nq][0], acc[mi][(HP_)*4 + nq], 0, 0, 0);               \
      acc[mi][(HP_)*4 + nq] = __builtin_amdgcn_mfma_f32_16x16x32_bf16(          \
          af[mi][1], bfr[nq][1], acc[mi][(HP_)*4 + nq], 0, 0, 0);               \
    }                                                                           \
    P0;                                                                         \
    if ((HP_) == 1) {                                                           \
      asm volatile("s_waitcnt vmcnt(0)");                                       \
      SB_;                                                                      \
    }                                                                           \
    BAR;                                                                        \
  } while (0)

  // ---- prologue: full tile 0; drain once ----
  STAGE_A(0, 0);
  STAGE_A(0, 1);
  STAGE_A(0, 2);
  STAGE_A(0, 3);
  STAGE_B(0, 0);
  STAGE_B(0, 1);
  __syncthreads();

  for (int tau = 0; tau < NTILES; ++tau) {
    PHASE(0, { STAGE_A(tau + 1, 0); STAGE_A(tau + 1, 1); STAGE_B(tau + 1, 0); });
    PHASE(1, { STAGE_A(tau + 1, 2); STAGE_A(tau + 1, 3); STAGE_B(tau + 1, 1); });  // + vmcnt(0)

    // ---- per-a-tile epilogue: tanh + v-weight -> atomic scores ----
    if ((tau & 15) == 15) {
      const int a0 = (tau >> 4) * BN;
      float w1v[8], vv[8];
#pragma unroll
      for (int ni = 0; ni < 8; ++ni) {
        const int a = a0 + wc * 128 + ni * 16 + lrow;
        w1v[ni] = w1q[(size_t)b * NA + a];
        vv[ni] = vvec[a];
      }
#pragma unroll
      for (int mi = 0; mi < 4; ++mi)
#pragma unroll
        for (int r = 0; r < 4; ++r) {
          float p = 0.f;
#pragma unroll
          for (int ni = 0; ni < 8; ++ni) {
            const float x = acc[mi][ni][r] + w1v[ni];
            const float e = __expf(2.f * x);
            p += (1.f - 2.f * __builtin_amdgcn_rcpf(e + 1.f)) * vv[ni];
          }
          p += __shfl_xor(p, 1);
          p += __shfl_xor(p, 2);
          p += __shfl_xor(p, 4);
          p += __shfl_xor(p, 8);
          if (lrow == 0)
            atomicAdd(&scores[bs0 + wr * 64 + mi * 16 + ko * 4 + r], p);
        }
#pragma unroll
      for (int mi = 0; mi < 4; ++mi)
#pragma unroll
        for (int ni = 0; ni < 8; ++ni) acc[mi][ni] = f32x4{0.f, 0.f, 0.f, 0.f};
    }
  }

#undef STAGE_A
#undef STAGE_B
#undef PHASE
#undef SB_
#undef P1
#undef P0
#undef BAR
}

// ---------------- masked softmax ----------------
__global__ __launch_bounds__(256) void softmax_kernel(const float* __restrict__ scores,
                                                      const int* __restrict__ mask,
                                                      float* __restrict__ out) {
  const int b = blockIdx.x;
  const int t = threadIdx.x;
  float sc[8];
  float mx = -3.4e38f;
#pragma unroll
  for (int j = 0; j < 8; ++j) {
    int i = t + j * 256;
    float s = scores[b * NS + i];
    if (mask[b * NS + i] == 0) s -= MASK_NEG;
    sc[j] = s;
    mx = fmaxf(mx, s);
  }
#pragma unroll
  for (int off = 1; off < 64; off <<= 1) mx = fmaxf(mx, __shfl_xor(mx, off));
  __shared__ float redm[4];
  __shared__ float reds[4];
  if ((t & 63) == 0) redm[t >> 6] = mx;
  __syncthreads();
  mx = fmaxf(fmaxf(redm[0], redm[1]), fmaxf(redm[2], redm[3]));
  float e[8];
  float sum = 0.f;
#pragma unroll
  for (int j = 0; j < 8; ++j) {
    e[j] = __expf(sc[j] - mx);
    sum += e[j];
  }
#pragma unroll
  for (int off = 1; off < 64; off <<= 1) sum += __shfl_xor(sum, off);
  if ((t & 63) == 0) reds[t >> 6] = sum;
  __syncthreads();
  sum = reds[0] + reds[1] + reds[2] + reds[3];
  float inv = 1.f / sum;
#pragma unroll
  for (int j = 0; j < 8; ++j) out[b * NS + t + j * 256] = e[j] * inv;
}

extern "C" void kernel_launch(void* const* d_in, const int* in_sizes, int n_in,
                              void* d_out, int out_size, void* d_ws, size_t ws_size,
                              hipStream_t stream) {
  const float* q = (const float*)d_in[0];
  const float* keysf = (const float*)d_in[1];
  const int* mask = (const int*)d_in[2];
  const float* W1 = (const float*)d_in[3];
  const float* W2f = (const float*)d_in[4];
  const float* v = (const float*)d_in[5];
  float* out = (float*)d_out;

  float* scores = (float*)d_ws;                                 // 256 KB
  float* w1q = scores + NB * NS;                                // 128 KB
  __bf16* W2b = (__bf16*)(w1q + NB * NA);                       // 2 MB

  zero_f32<<<NB * NS / 256, 256, 0, stream>>>(scores, NB * NS);
  cvt_bf16<<<512, 256, 0, stream>>>(W2f, W2b, NA * ND / 8);
  w1q_kernel<<<dim3(NB, NA / 64), 256, 0, stream>>>(q, W1, w1q);
  score_gemm<<<NB * NS / BM, 512, 0, stream>>>(keysf, W2b, w1q, v, scores);
  softmax_kernel<<<NB, 256, 0, stream>>>(scores, mask, out);
}